// Round 1
// 852.998 us; speedup vs baseline: 1.0565x; 1.0565x over previous
//
#include <hip/hip_runtime.h>

// CrossAttentionLayer: QKV proj -> scores(out#2) -> softmax (no-max, exp-sum) -> PV -> O proj -> +resid -> LN(out#1)
// R1: fixed half-covered staging (NaN).
// R2: m97-structure GEMMs (global_load_lds 16B, linear LDS, fused QKV launch);
//     V pre-transposed once to Vt[B,NH,HD,LKV] (kills 16-way-conflicted in-loop transpose);
//     attn: dbuf K/V via global_load_lds w/ pre-swizzled source + XOR-swizzled reads (conflict-free),
//     1 barrier/tile (P is same-wave-only -> no second barrier), nontemporal score stores.

typedef __bf16 bf16x8 __attribute__((ext_vector_type(8)));
typedef float f32x4 __attribute__((ext_vector_type(4)));

constexpr int cH = 1024, cNH = 16, cHD = 64, cB = 2, cLQ = 1024, cLKV = 4096;

__device__ __forceinline__ unsigned short f2b(float f) {
    union { float f; unsigned u; } v; v.f = f;
    unsigned u = v.u;
    return (unsigned short)((u + 0x7fffu + ((u >> 16) & 1u)) >> 16);
}

__device__ __forceinline__ unsigned short bf16r(float f) {
    union { __bf16 h; unsigned short u; } v; v.h = (__bf16)f; return v.u;
}

// async global->LDS, 16B per lane. LDS dest must be wave-uniform base + lane*16 (it is: idx = t + i*256).
__device__ __forceinline__ void gload16(const void* g, void* l) {
    __builtin_amdgcn_global_load_lds((const __attribute__((address_space(1))) void*)g,
                                     (__attribute__((address_space(3))) void*)l, 16, 0, 0);
}

__global__ void cvt_kernel(const float* __restrict__ src, unsigned short* __restrict__ dst, int n4) {
    int i = blockIdx.x * blockDim.x + threadIdx.x;
    int stride = gridDim.x * blockDim.x;
    for (; i < n4; i += stride) {
        float4 f = ((const float4*)src)[i];
        ushort4 o;
        o.x = f2b(f.x); o.y = f2b(f.y); o.z = f2b(f.z); o.w = f2b(f.w);
        ((ushort4*)dst)[i] = o;
    }
}

// C[M,N] = A[M,K] @ W[N,K]^T + bias  (K=N=1024). EPI=0: bf16 out. EPI=1: fp32 out + residual.
// m97 structure: linear [128][64] LDS tiles filled by global_load_lds_dwordx4, 2 barriers per K-step.
template<int EPI>
__device__ __forceinline__ void gemm_core(
    const unsigned short* __restrict__ A,
    const unsigned short* __restrict__ W,
    const float* __restrict__ bias,
    const float* __restrict__ resid,
    void* __restrict__ Cout,
    int m0, int n0)
{
    constexpr int K = 1024, N = 1024;
    __shared__ unsigned short Asm_[128 * 64];
    __shared__ unsigned short Bsm_[128 * 64];
    const int t = threadIdx.x;
    const int wv = t >> 6, lane = t & 63, quad = lane >> 4, l16 = lane & 15;
    const int wm = (wv & 1) * 64, wn = (wv >> 1) * 64;
    const int sr = t >> 3, sc8 = (t & 7) * 8;

    f32x4 acc[4][4];
#pragma unroll
    for (int i = 0; i < 4; i++)
#pragma unroll
        for (int j = 0; j < 4; j++) acc[i][j] = f32x4{0.f, 0.f, 0.f, 0.f};

    for (int k0 = 0; k0 < K; k0 += 64) {
        __syncthreads();
#pragma unroll
        for (int i = 0; i < 4; i++) {
            int rr = sr + i * 32;
            gload16(&A[(size_t)(m0 + rr) * K + k0 + sc8], &Asm_[(t + i * 256) * 8]);
            gload16(&W[(size_t)(n0 + rr) * K + k0 + sc8], &Bsm_[(t + i * 256) * 8]);
        }
        __syncthreads();   // compiler drains vmcnt here -> tiles ready
#pragma unroll
        for (int ks = 0; ks < 64; ks += 32) {
            bf16x8 af[4], bfr[4];
#pragma unroll
            for (int i = 0; i < 4; i++)
                af[i] = *(const bf16x8*)(&Asm_[(wm + 16 * i + l16) * 64 + ks + quad * 8]);
#pragma unroll
            for (int j = 0; j < 4; j++)
                bfr[j] = *(const bf16x8*)(&Bsm_[(wn + 16 * j + l16) * 64 + ks + quad * 8]);
#pragma unroll
            for (int i = 0; i < 4; i++)
#pragma unroll
                for (int j = 0; j < 4; j++)
                    acc[i][j] = __builtin_amdgcn_mfma_f32_16x16x32_bf16(af[i], bfr[j], acc[i][j], 0, 0, 0);
        }
    }
    // epilogue: C row = quad*4+reg, col = lane&15 (verified m89/m91 layout)
#pragma unroll
    for (int i = 0; i < 4; i++) {
#pragma unroll
        for (int j = 0; j < 4; j++) {
            int n = n0 + wn + 16 * j + l16;
            float bv = bias[n];
#pragma unroll
            for (int r = 0; r < 4; r++) {
                int m = m0 + wm + 16 * i + quad * 4 + r;
                float v = acc[i][j][r] + bv;
                if (EPI == 0) {
                    ((unsigned short*)Cout)[(size_t)m * N + n] = bf16r(v);
                } else {
                    v += resid[(size_t)m * N + n];
                    ((float*)Cout)[(size_t)m * N + n] = v;
                }
            }
        }
    }
}

// Fused Q/K/V projection: grid (64, 8, 3); z=0: Q (M=2048, 48 of 64 x-blocks early-exit), z=1: K, z=2: V.
__global__ __launch_bounds__(256) void gemm_qkv(
    const unsigned short* __restrict__ hid, const unsigned short* __restrict__ enc,
    const unsigned short* __restrict__ qw, const unsigned short* __restrict__ kw,
    const unsigned short* __restrict__ vw,
    const float* __restrict__ qb, const float* __restrict__ kb, const float* __restrict__ vb,
    unsigned short* __restrict__ Qo, unsigned short* __restrict__ Ko, unsigned short* __restrict__ Vo)
{
    const int z = blockIdx.z;
    const int M = (z == 0) ? cB * cLQ : cB * cLKV;
    if ((int)blockIdx.x * 128 >= M) return;
    const unsigned short* A = (z == 0) ? hid : enc;
    const unsigned short* W = (z == 0) ? qw : (z == 1) ? kw : vw;
    const float* bias = (z == 0) ? qb : (z == 1) ? kb : vb;
    unsigned short* C = (z == 0) ? Qo : (z == 1) ? Ko : Vo;
    gemm_core<0>(A, W, bias, nullptr, (void*)C, blockIdx.x * 128, blockIdx.y * 128);
}

__global__ __launch_bounds__(256) void gemm_o(
    const unsigned short* __restrict__ A, const unsigned short* __restrict__ W,
    const float* __restrict__ bias, const float* __restrict__ resid, float* __restrict__ C)
{
    gemm_core<1>(A, W, bias, resid, (void*)C, blockIdx.x * 128, blockIdx.y * 128);
}

// Vb [B*LKV, H] -> Vt [B, NH, HD, LKV].  XOR-swizzled LDS tile: content chunk g of row kv lives at
// chunk g ^ kkey(kv), kkey(kv) = (kv ^ (kv>>3)) & 7  -> column-gather reads are ~2-way (free).
__global__ __launch_bounds__(256) void vtrans_kernel(const unsigned short* __restrict__ Vb,
                                                     unsigned short* __restrict__ Vt)
{
    __shared__ unsigned short T[64 * 64];
    const int kv0 = blockIdx.x * 64, h = blockIdx.y, b = blockIdx.z;
    const int t = threadIdx.x;
    const int r = t >> 3, c = t & 7;
#pragma unroll
    for (int i = 0; i < 2; i++) {
        int rr = r + i * 32;            // kv row
        bf16x8 v = *(const bf16x8*)(&Vb[(size_t)(b * cLKV + kv0 + rr) * cH + h * cHD + c * 8]);
        int ch = c ^ ((rr ^ (rr >> 3)) & 7);
        *(bf16x8*)(&T[rr * 64 + ch * 8]) = v;
    }
    __syncthreads();
#pragma unroll
    for (int i = 0; i < 2; i++) {
        int rd = r + i * 32;            // d row
        union { bf16x8 v; unsigned short s[8]; } u;
#pragma unroll
        for (int j = 0; j < 8; j++) {
            int kv = c * 8 + j;
            int ch = (rd >> 3) ^ ((kv ^ (kv >> 3)) & 7);
            u.s[j] = T[kv * 64 + (ch << 3) + (rd & 7)];
        }
        *(bf16x8*)(&Vt[((size_t)(b * cNH + h) * cHD + rd) * cLKV + kv0 + c * 8]) = u.v;
    }
}

// One WG (4 waves) per (b, h, 64-row q tile). Double-buffered K/V tiles via global_load_lds with
// pre-swizzled global source (chunk sc holds global chunk sc ^ (row&7)); swizzled reads -> conflict-free.
// ONE barrier per tile: P tile is written & read by the same wave only (rows wv*16..+16).
__global__ __launch_bounds__(256) void attn_kernel(
    const unsigned short* __restrict__ Qb,   // [B*LQ, H] bf16
    const unsigned short* __restrict__ Kb,   // [B*LKV, H] bf16
    const unsigned short* __restrict__ Vt,   // [B, NH, HD, LKV] bf16
    const int* __restrict__ mask,            // [B, LKV]
    float* __restrict__ scores,              // [B,NH,LQ,LKV] fp32
    unsigned short* __restrict__ ctx)        // [B*LQ, H] bf16 (merged heads)
{
    __shared__ unsigned short Qs[64 * 64];
    __shared__ unsigned short Ks[2][64 * 64];
    __shared__ unsigned short Vs[2][64 * 64];
    __shared__ unsigned short Ps[64 * 64];
    __shared__ int Ms[2][64];

    const int qt = blockIdx.x, h = blockIdx.y, b = blockIdx.z;
    const int t = threadIdx.x;
    const int wv = t >> 6, lane = t & 63, quad = lane >> 4, l16 = lane & 15;
    const int q0 = qt * 64;
    const int sr = t >> 3, sc = t & 7;

    const unsigned short* Kbase = Kb + (size_t)b * cLKV * cH + h * cHD;
    const unsigned short* Vbase = Vt + ((size_t)(b * cNH + h) * cHD) * cLKV;

    // stage Q once (swizzled source -> linear LDS)
#pragma unroll
    for (int i = 0; i < 2; i++) {
        int rr = sr + i * 32;
        int cc = (sc ^ (rr & 7)) * 8;
        gload16(&Qb[(size_t)(b * cLQ + q0 + rr) * cH + h * cHD + cc], &Qs[(t + i * 256) * 8]);
    }
    // stage K/V tile 0
#pragma unroll
    for (int i = 0; i < 2; i++) {
        int rr = sr + i * 32;
        int cc = (sc ^ (rr & 7)) * 8;
        gload16(&Kbase[(size_t)rr * cH + cc], &Ks[0][(t + i * 256) * 8]);
        gload16(&Vbase[(size_t)rr * cLKV + cc], &Vs[0][(t + i * 256) * 8]);
    }
    if (t < 64) Ms[0][t] = mask[b * cLKV + t];

    f32x4 cacc[4];
#pragma unroll
    for (int j = 0; j < 4; j++) cacc[j] = f32x4{0.f, 0.f, 0.f, 0.f};
    float rs[4] = {0.f, 0.f, 0.f, 0.f};

    float* srow = scores + (size_t)(b * cNH + h) * cLQ * cLKV;
    const int qr = wv * 16 + l16;

    for (int it = 0; it < cLKV / 64; ++it) {
        const int kv0 = it * 64, cur = it & 1;
        __syncthreads();   // drains vmcnt: buf[cur] ready; all waves done reading buf[cur^1]
        if (it + 1 < cLKV / 64) {
            const int kv1 = kv0 + 64;
#pragma unroll
            for (int i = 0; i < 2; i++) {
                int rr = sr + i * 32;
                int cc = (sc ^ (rr & 7)) * 8;
                gload16(&Kbase[(size_t)(kv1 + rr) * cH + cc], &Ks[cur ^ 1][(t + i * 256) * 8]);
                gload16(&Vbase[(size_t)rr * cLKV + kv1 + cc], &Vs[cur ^ 1][(t + i * 256) * 8]);
            }
            if (t < 64) Ms[cur ^ 1][t] = mask[b * cLKV + kv1 + t];
        }

        // S = Q K^T for this wave's 16 q-rows x 64 kv-cols
        f32x4 sacc[4];
#pragma unroll
        for (int j = 0; j < 4; j++) sacc[j] = f32x4{0.f, 0.f, 0.f, 0.f};
#pragma unroll
        for (int ks = 0; ks < 64; ks += 32) {
            const int ec = (ks >> 3) + quad;
            bf16x8 aq = *(const bf16x8*)(&Qs[qr * 64 + ((ec ^ (qr & 7)) << 3)]);
#pragma unroll
            for (int nt = 0; nt < 4; nt++) {
                int kr = nt * 16 + l16;
                bf16x8 bk = *(const bf16x8*)(&Ks[cur][kr * 64 + ((ec ^ (kr & 7)) << 3)]);
                sacc[nt] = __builtin_amdgcn_mfma_f32_16x16x32_bf16(aq, bk, sacc[nt], 0, 0, 0);
            }
        }

        // scale, mask, store scores (nontemporal: write-once), exp, rowsum partials, P -> swizzled LDS
#pragma unroll
        for (int nt = 0; nt < 4; nt++) {
            const int col = nt * 16 + l16;
            const bool live = (Ms[cur][col] != 0);
#pragma unroll
            for (int r4 = 0; r4 < 4; r4++) {
                const int qrow = wv * 16 + quad * 4 + r4;
                float s = sacc[nt][r4] * 0.125f;
                float sv = live ? s : -__builtin_inff();
                __builtin_nontemporal_store(sv, &srow[(size_t)(q0 + qrow) * cLKV + kv0 + col]);
                float p = live ? __expf(s) : 0.f;
                rs[r4] += p;
                Ps[qrow * 64 + ((((col >> 3) ^ (qrow & 7)) << 3) | (col & 7))] = bf16r(p);
            }
        }

        // ctx += P @ V  (same-wave P rows -> no barrier needed; lgkmcnt orders write->read)
#pragma unroll
        for (int ks = 0; ks < 64; ks += 32) {
            const int ec = (ks >> 3) + quad;
            bf16x8 ap = *(const bf16x8*)(&Ps[qr * 64 + ((ec ^ (qr & 7)) << 3)]);
#pragma unroll
            for (int dt = 0; dt < 4; dt++) {
                int dr = dt * 16 + l16;
                bf16x8 bv = *(const bf16x8*)(&Vs[cur][dr * 64 + ((ec ^ (dr & 7)) << 3)]);
                cacc[dt] = __builtin_amdgcn_mfma_f32_16x16x32_bf16(ap, bv, cacc[dt], 0, 0, 0);
            }
        }
    }

    // finalize row sums: reduce across the 16 lanes of each quad
#pragma unroll
    for (int r = 0; r < 4; r++) {
        float v = rs[r];
        v += __shfl_xor(v, 1);
        v += __shfl_xor(v, 2);
        v += __shfl_xor(v, 4);
        v += __shfl_xor(v, 8);
        rs[r] = v;
    }
#pragma unroll
    for (int dt = 0; dt < 4; dt++) {
#pragma unroll
        for (int r = 0; r < 4; r++) {
            int qrow = wv * 16 + quad * 4 + r;
            ctx[(size_t)(b * cLQ + q0 + qrow) * cH + h * cHD + dt * 16 + l16] = bf16r(cacc[dt][r] / rs[r]);
        }
    }
}

__global__ __launch_bounds__(256) void ln_kernel(
    const float* __restrict__ y,
    const float* __restrict__ lw,
    const float* __restrict__ lb,
    float* __restrict__ out)
{
    __shared__ float red[8];
    const int row = blockIdx.x, t = threadIdx.x;
    const float* yr = y + (size_t)row * cH;
    float4 v = ((const float4*)yr)[t];
    float s1 = v.x + v.y + v.z + v.w;
    float s2 = v.x * v.x + v.y * v.y + v.z * v.z + v.w * v.w;
#pragma unroll
    for (int o = 1; o < 64; o <<= 1) {
        s1 += __shfl_xor(s1, o);
        s2 += __shfl_xor(s2, o);
    }
    if ((t & 63) == 0) { red[t >> 6] = s1; red[4 + (t >> 6)] = s2; }
    __syncthreads();
    s1 = red[0] + red[1] + red[2] + red[3];
    s2 = red[4] + red[5] + red[6] + red[7];
    float mu = s1 * (1.f / 1024.f);
    float var = s2 * (1.f / 1024.f) - mu * mu;
    float inv = rsqrtf(fmaxf(var, 0.f) + 1e-12f);
    float4 w4 = ((const float4*)lw)[t];
    float4 b4 = ((const float4*)lb)[t];
    float4 o4;
    o4.x = (v.x - mu) * inv * w4.x + b4.x;
    o4.y = (v.y - mu) * inv * w4.y + b4.y;
    o4.z = (v.z - mu) * inv * w4.z + b4.z;
    o4.w = (v.w - mu) * inv * w4.w + b4.w;
    ((float4*)(out + (size_t)row * cH))[t] = o4;
}

extern "C" void kernel_launch(void* const* d_in, const int* in_sizes, int n_in,
                              void* d_out, int out_size, void* d_ws, size_t ws_size,
                              hipStream_t stream) {
    (void)in_sizes; (void)n_in; (void)out_size; (void)ws_size;
    const float* hidden = (const float*)d_in[0];
    const float* enc    = (const float*)d_in[1];
    const int*   mask   = (const int*)d_in[2];
    const float* q_w = (const float*)d_in[3];
    const float* q_b = (const float*)d_in[4];
    const float* k_w = (const float*)d_in[5];
    const float* k_b = (const float*)d_in[6];
    const float* v_w = (const float*)d_in[7];
    const float* v_b = (const float*)d_in[8];
    const float* o_w = (const float*)d_in[9];
    const float* o_b = (const float*)d_in[10];
    const float* lnw = (const float*)d_in[11];
    const float* lnb = (const float*)d_in[12];

    char* ws = (char*)d_ws;
    unsigned short* hid_b = (unsigned short*)(ws);                        // 4 MiB
    unsigned short* enc_b = (unsigned short*)(ws + ((size_t)4  << 20));   // 16 MiB
    unsigned short* qw_b  = (unsigned short*)(ws + ((size_t)20 << 20));   // 2 MiB
    unsigned short* kw_b  = (unsigned short*)(ws + ((size_t)22 << 20));
    unsigned short* vw_b  = (unsigned short*)(ws + ((size_t)24 << 20));
    unsigned short* ow_b  = (unsigned short*)(ws + ((size_t)26 << 20));
    unsigned short* Qb    = (unsigned short*)(ws + ((size_t)28 << 20));   // 4 MiB
    unsigned short* Kb    = (unsigned short*)(ws + ((size_t)32 << 20));   // 16 MiB
    unsigned short* Vb    = (unsigned short*)(ws + ((size_t)48 << 20));   // 16 MiB
    unsigned short* ctxb  = (unsigned short*)(ws + ((size_t)64 << 20));   // 4 MiB
    float*          yb    = (float*)(ws + ((size_t)68 << 20));            // 8 MiB
    unsigned short* Vt    = (unsigned short*)(ws + ((size_t)76 << 20));   // 16 MiB

    float* out_ln = (float*)d_out;
    float* out_sc = (float*)d_out + (size_t)cB * cLQ * cH;

    // fp32 -> bf16 staging
    cvt_kernel<<<(cB * cLQ * cH / 4 + 255) / 256, 256, 0, stream>>>(hidden, hid_b, cB * cLQ * cH / 4);
    cvt_kernel<<<(cB * cLKV * cH / 4 + 255) / 256, 256, 0, stream>>>(enc, enc_b, cB * cLKV * cH / 4);
    cvt_kernel<<<(cH * cH / 4 + 255) / 256, 256, 0, stream>>>(q_w, qw_b, cH * cH / 4);
    cvt_kernel<<<(cH * cH / 4 + 255) / 256, 256, 0, stream>>>(k_w, kw_b, cH * cH / 4);
    cvt_kernel<<<(cH * cH / 4 + 255) / 256, 256, 0, stream>>>(v_w, vw_b, cH * cH / 4);
    cvt_kernel<<<(cH * cH / 4 + 255) / 256, 256, 0, stream>>>(o_w, ow_b, cH * cH / 4);

    // fused Q/K/V projections (z-dim selects), then V transpose for attn's B-operand layout
    gemm_qkv<<<dim3(64, 8, 3), 256, 0, stream>>>(hid_b, enc_b, qw_b, kw_b, vw_b,
                                                 q_b, k_b, v_b, Qb, Kb, Vb);
    vtrans_kernel<<<dim3(cLKV / 64, cNH, cB), 256, 0, stream>>>(Vb, Vt);

    // fused scores + softmax + PV
    attn_kernel<<<dim3(cLQ / 64, cNH, cB), 256, 0, stream>>>(Qb, Kb, Vt, mask, out_sc, ctxb);

    // output projection + bias + residual, then LayerNorm
    gemm_o<<<dim3(cB * cLQ / 128, 8), 256, 0, stream>>>(ctxb, ow_b, o_b, hidden, yb);
    ln_kernel<<<cB * cLQ, 256, 0, stream>>>(yb, lnw, lnb, out_ln);
}